// Round 1
// baseline (849.600 us; speedup 1.0000x reference)
//
#include <hip/hip_runtime.h>
#include <stdint.h>

// XLA emits multiply and add as separate uncontracted HLOs; HIP's default
// -ffp-contract=fast would fuse them into fma and break bit-exact RNG/score
// reproduction. Kill contraction globally.
#pragma clang fp contract(off)

// JAX >= 0.5.0 defaults jax_threefry_partitionable=True (counter = flat index,
// bits = out0 ^ out1). Set to 0 for the legacy iota-split stream if the bench
// shows full-range absmax mismatch.
#define JAX_PARTITIONABLE 1

struct Keys { uint32_t k[12]; };  // [dir(2)][rs-step(3)][2 words]

// ---- Threefry-2x32, 20 rounds, exact JAX schedule ----
__host__ __device__ inline void tf2x32(uint32_t k0, uint32_t k1,
                                       uint32_t x0, uint32_t x1,
                                       uint32_t* o0, uint32_t* o1) {
  const uint32_t ks2 = k0 ^ k1 ^ 0x1BD11BDAu;
  x0 += k0; x1 += k1;
#define TF_R(r) { x0 += x1; x1 = (x1 << (r)) | (x1 >> (32 - (r))); x1 ^= x0; }
  TF_R(13) TF_R(15) TF_R(26) TF_R(6)
  x0 += k1;  x1 += ks2 + 1u;
  TF_R(17) TF_R(29) TF_R(16) TF_R(24)
  x0 += ks2; x1 += k0 + 2u;
  TF_R(13) TF_R(15) TF_R(26) TF_R(6)
  x0 += k0;  x1 += k1 + 3u;
  TF_R(17) TF_R(29) TF_R(16) TF_R(24)
  x0 += k1;  x1 += ks2 + 4u;
  TF_R(13) TF_R(15) TF_R(26) TF_R(6)
  x0 += ks2; x1 += k0 + 5u;
#undef TF_R
  *o0 = x0; *o1 = x1;
}

// ---- XLA ErfInv32 (Giles coefficients, exact op order) ----
__device__ inline float erfinv_xla(float x) {
#pragma clang fp contract(off)
  float w = -log1pf(-(x * x));
  float p;
  if (w < 5.0f) {
    w = w - 2.5f;
    p = 2.81022636e-08f;
    p = 3.43273939e-07f  + p * w;
    p = -3.5233877e-06f  + p * w;
    p = -4.39150654e-06f + p * w;
    p = 0.00021858087f   + p * w;
    p = -0.00125372503f  + p * w;
    p = -0.00417768164f  + p * w;
    p = 0.246640727f     + p * w;
    p = 1.50140941f      + p * w;
  } else {
    w = sqrtf(w) - 3.0f;
    p = -0.000200214257f;
    p = 0.000100950558f  + p * w;
    p = 0.00134934322f   + p * w;
    p = -0.00367342844f  + p * w;
    p = 0.00573950773f   + p * w;
    p = -0.0076224613f   + p * w;
    p = 0.00943887047f   + p * w;
    p = 1.00167406f      + p * w;
    p = 2.83297682f      + p * w;
  }
  return p * x;
}

// jax.random.normal element `idx` of a (4,64,64,2) f32 draw under key (k0,k1).
__device__ inline float jax_normal(uint32_t k0, uint32_t k1, uint32_t idx) {
#pragma clang fp contract(off)
  uint32_t o0, o1, bits;
#if JAX_PARTITIONABLE
  tf2x32(k0, k1, 0u, idx, &o0, &o1);
  bits = o0 ^ o1;
#else
  if (idx < 16384u) { tf2x32(k0, k1, idx, idx + 16384u, &o0, &o1); bits = o0; }
  else              { tf2x32(k0, k1, idx - 16384u, idx, &o0, &o1); bits = o1; }
#endif
  float f = __uint_as_float((bits >> 9) | 0x3f800000u) - 1.0f;
  // uniform in [lo, 1): lo = nextafterf(-1,0); (hi-lo) rounds to exactly 2.0f
  float u = f * 2.0f + (-0x1.fffffep-1f);
  u = fmaxf(-0x1.fffffep-1f, u);
  return 0x1.6a09e6p+0f * erfinv_xla(u);  // float(sqrt(2)) * erfinv(u)
}

// Bilinear corr score; association matches XLA: ((t00+t01)+t10)+t11.
__device__ inline float score_at(const float* __restrict__ base, int stride,
                                 float x, float y) {
#pragma clang fp contract(off)
  float x0 = floorf(x), y0 = floorf(y);
  float wx = x - x0, wy = y - y0;
  int xi = (int)x0; xi = xi < 0 ? 0 : (xi > 63 ? 63 : xi);
  int yi = (int)y0; yi = yi < 0 ? 0 : (yi > 63 ? 63 : yi);
  int x1 = xi + 1 > 63 ? 63 : xi + 1;
  int y1 = yi + 1 > 63 ? 63 : yi + 1;
  float v00 = base[(yi * 64 + xi) * stride];
  float v01 = base[(yi * 64 + x1) * stride];
  float v10 = base[(y1 * 64 + xi) * stride];
  float v11 = base[(y1 * 64 + x1) * stride];
  float omx = 1.0f - wx, omy = 1.0f - wy;
  return (((v00 * omx) * omy + (v01 * wx) * omy) + (v10 * omx) * wy) + (v11 * wx) * wy;
}

__device__ __forceinline__ void corr_base(const float* __restrict__ corr, int dir,
                                          int b, int p, const float** base, int* stride) {
  if (dir == 0) { *base = corr + (size_t)(b * 4096 + p) * 4096; *stride = 1; }
  else          { *base = corr + (size_t)b * 16777216 + p;      *stride = 4096; }
}

__device__ __forceinline__ void prop_step(float2* sc, const float* __restrict__ corr,
                                          int dir, int b, int dx, int dy) {
#pragma clang fp contract(off)
  const int tid = threadIdx.x;
  float2 best[4];
  for (int t = 0; t < 4; ++t) {
    int p = tid + t * 1024;
    int i = p >> 6, j = p & 63;
    const float* base; int stride;
    corr_base(corr, dir, b, p, &base, &stride);
    float2 c  = sc[p];
    float2 ch = sc[(i << 6) | ((j - dx) & 63)];       // roll along W
    float2 cv = sc[(((i - dy) & 63) << 6) | j];        // roll along H
    ch.x = fminf(fmaxf(ch.x + (float)dx, 0.0f), 63.0f);  // + [dx,0], clamp
    cv.y = fminf(fmaxf(cv.y + (float)dy, 0.0f), 63.0f);  // + [0,dy], clamp
    float s0 = score_at(base, stride, c.x,  c.y);
    float sh = score_at(base, stride, ch.x, ch.y);
    float sv = score_at(base, stride, cv.x, cv.y);
    float2 bst = c; float bs = s0;
    if (sh > bs) bst = ch;                // upd = s > best_s
    bs = fmaxf(sh, bs);
    if (sv > bs) bst = cv;
    bs = fmaxf(sv, bs);
    best[t] = bst;
  }
  __syncthreads();                        // all neighbor reads done
  for (int t = 0; t < 4; ++t) sc[tid + t * 1024] = best[t];
  __syncthreads();
}

__device__ __forceinline__ void rs_step(float2* sc, const float* __restrict__ corr,
                                        int dir, int b, uint32_t k0, uint32_t k1) {
#pragma clang fp contract(off)
  const int tid = threadIdx.x;
  for (int t = 0; t < 4; ++t) {
    int p = tid + t * 1024;
    const float* base; int stride;
    corr_base(corr, dir, b, p, &base, &stride);
    uint32_t pg = (uint32_t)(b * 4096 + p);        // flat (b,i,j) over (4,64,64)
    float2 c = sc[p];
    float n0 = jax_normal(k0, k1, 2u * pg);
    float n1 = jax_normal(k0, k1, 2u * pg + 1u);
    float nx = fminf(fmaxf(c.x + 3.0f * n0, 0.0f), 63.0f);  // coords + R*normal, clamp
    float ny = fminf(fmaxf(c.y + 3.0f * n1, 0.0f), 63.0f);
    float so = score_at(base, stride, c.x, c.y);
    float sn = score_at(base, stride, nx, ny);
    if (sn - so > 0.0f) sc[p] = make_float2(nx, ny);  // new_s - 1.0*old_s > 0
  }
  __syncthreads();
}

// One block per (direction, batch): state = 4096 float2 in LDS, 7-step chain.
__global__ __launch_bounds__(1024) void pm_kernel(const float* __restrict__ mf,
                                                  const float* __restrict__ mb,
                                                  const float* __restrict__ corr,
                                                  float2* __restrict__ res, Keys keys) {
  __shared__ float2 sc[4096];
  const int tid = threadIdx.x;
  const int dir = (int)(blockIdx.x >> 2);
  const int b   = (int)(blockIdx.x & 3);
  const float* m = (dir == 0) ? mf : mb;
  for (int t = 0; t < 4; ++t) {
    int p = tid + t * 1024;
    int i = p >> 6, j = p & 63;
    sc[p] = make_float2(m[((b * 2 + 0) * 64 + i) * 64 + j],
                        m[((b * 2 + 1) * 64 + i) * 64 + j]);
  }
  __syncthreads();
  const uint32_t* kk = &keys.k[dir * 6];
  prop_step(sc, corr, dir, b,  1,  1);
  rs_step  (sc, corr, dir, b, kk[0], kk[1]);
  prop_step(sc, corr, dir, b, -1, -1);
  rs_step  (sc, corr, dir, b, kk[2], kk[3]);
  prop_step(sc, corr, dir, b, -1,  1);
  rs_step  (sc, corr, dir, b, kk[4], kk[5]);
  prop_step(sc, corr, dir, b,  1, -1);
  for (int t = 0; t < 4; ++t) {
    int p = tid + t * 1024;
    res[dir * 16384 + b * 4096 + p] = sc[p];
  }
}

// Bilinear-sample res_b at res_f, fwd-bwd consistency, transpose to (B,2,H,W).
__global__ __launch_bounds__(256) void combine_kernel(const float* __restrict__ mf,
                                                      const float2* __restrict__ res,
                                                      float* __restrict__ out) {
#pragma clang fp contract(off)
  int pg = (int)(blockIdx.x * 256 + threadIdx.x);   // 0..16383
  int b = pg >> 12, hw = pg & 4095;
  int i = hw >> 6, j = hw & 63;
  float2 rf = res[pg];
  const float2* rb = res + 16384 + b * 4096;
  float x0 = floorf(rf.x), y0 = floorf(rf.y);
  float wx = rf.x - x0, wy = rf.y - y0;
  int xi = (int)x0; xi = xi < 0 ? 0 : (xi > 63 ? 63 : xi);
  int yi = (int)y0; yi = yi < 0 ? 0 : (yi > 63 ? 63 : yi);
  int x1 = xi + 1 > 63 ? 63 : xi + 1;
  int y1 = yi + 1 > 63 ? 63 : yi + 1;
  float2 v00 = rb[yi * 64 + xi], v01 = rb[yi * 64 + x1];
  float2 v10 = rb[y1 * 64 + xi], v11 = rb[y1 * 64 + x1];
  float omx = 1.0f - wx, omy = 1.0f - wy;
  float c0 = (((v00.x * omx) * omy + (v01.x * wx) * omy) + (v10.x * omx) * wy) + (v11.x * wx) * wy;
  float c1 = (((v00.y * omx) * omy + (v01.y * wx) * omy) + (v10.y * omx) * wy) + (v11.y * wx) * wy;
  float d = fmaxf(fabsf(rf.x - c0), fabsf(rf.y - c1));
  bool invalid = d > 0.01f;
  out[((b * 2 + 0) * 64 + i) * 64 + j] = invalid ? mf[((b * 2 + 0) * 64 + i) * 64 + j] : rf.x;
  out[((b * 2 + 1) * 64 + i) * 64 + j] = invalid ? mf[((b * 2 + 1) * 64 + i) * 64 + j] : rf.y;
}

extern "C" void kernel_launch(void* const* d_in, const int* in_sizes, int n_in,
                              void* d_out, int out_size, void* d_ws, size_t ws_size,
                              hipStream_t stream) {
  const float* mf   = (const float*)d_in[0];
  const float* mb   = (const float*)d_in[1];
  const float* corr = (const float*)d_in[2];
  float* out  = (float*)d_out;
  float2* res = (float2*)d_ws;   // [2][16384] float2 = 256 KB scratch

  // Host-side key derivation from seed 42 -> root key (0, 42).
  Keys K;
#if JAX_PARTITIONABLE
  uint32_t kf0, kf1, kb0, kb1;
  tf2x32(0u, 42u, 0u, 0u, &kf0, &kf1);   // split(root,2)[0] = kf
  tf2x32(0u, 42u, 0u, 1u, &kb0, &kb1);   // split(root,2)[1] = kb
  for (uint32_t s = 0; s < 3; ++s) {     // split(k,3)[s] = enc_k(0, s)
    tf2x32(kf0, kf1, 0u, s, &K.k[0 + s * 2], &K.k[0 + s * 2 + 1]);
    tf2x32(kb0, kb1, 0u, s, &K.k[6 + s * 2], &K.k[6 + s * 2 + 1]);
  }
#else
  {
    // legacy: split(root,2): pairs (0,2),(1,3); kf=(A0,B0), kb=(A1,B1)
    uint32_t a0, a1, c0, c1;
    tf2x32(0u, 42u, 0u, 2u, &a0, &a1);
    tf2x32(0u, 42u, 1u, 3u, &c0, &c1);
    uint32_t kf0 = a0, kf1 = c0, kb0 = a1, kb1 = c1;
    uint32_t u0, u1, v0, v1, w0, w1;
    // split(k,3): pairs (0,3),(1,4),(2,5); k1=(U0,V0) k2=(W0,U1) k3=(V1,W1)
    tf2x32(kf0, kf1, 0u, 3u, &u0, &u1);
    tf2x32(kf0, kf1, 1u, 4u, &v0, &v1);
    tf2x32(kf0, kf1, 2u, 5u, &w0, &w1);
    K.k[0] = u0; K.k[1] = v0; K.k[2] = w0; K.k[3] = u1; K.k[4] = v1; K.k[5] = w1;
    tf2x32(kb0, kb1, 0u, 3u, &u0, &u1);
    tf2x32(kb0, kb1, 1u, 4u, &v0, &v1);
    tf2x32(kb0, kb1, 2u, 5u, &w0, &w1);
    K.k[6] = u0; K.k[7] = v0; K.k[8] = w0; K.k[9] = u1; K.k[10] = v1; K.k[11] = w1;
  }
#endif

  pm_kernel<<<dim3(8), dim3(1024), 0, stream>>>(mf, mb, corr, res, K);
  combine_kernel<<<dim3(64), dim3(256), 0, stream>>>(mf, res, out);
  (void)in_sizes; (void)n_in; (void)out_size; (void)ws_size;
}

// Round 2
// 334.449 us; speedup vs baseline: 2.5403x; 2.5403x over previous
//
#include <hip/hip_runtime.h>
#include <stdint.h>

// XLA emits multiply and add as separate uncontracted HLOs; HIP's default
// -ffp-contract=fast would fuse them into fma and break bit-exact RNG/score
// reproduction. Kill contraction globally.
#pragma clang fp contract(off)

// ---- Threefry-2x32, 20 rounds, exact JAX schedule ----
__host__ __device__ inline void tf2x32(uint32_t k0, uint32_t k1,
                                       uint32_t x0, uint32_t x1,
                                       uint32_t* o0, uint32_t* o1) {
  const uint32_t ks2 = k0 ^ k1 ^ 0x1BD11BDAu;
  x0 += k0; x1 += k1;
#define TF_R(r) { x0 += x1; x1 = (x1 << (r)) | (x1 >> (32 - (r))); x1 ^= x0; }
  TF_R(13) TF_R(15) TF_R(26) TF_R(6)
  x0 += k1;  x1 += ks2 + 1u;
  TF_R(17) TF_R(29) TF_R(16) TF_R(24)
  x0 += ks2; x1 += k0 + 2u;
  TF_R(13) TF_R(15) TF_R(26) TF_R(6)
  x0 += k0;  x1 += k1 + 3u;
  TF_R(17) TF_R(29) TF_R(16) TF_R(24)
  x0 += k1;  x1 += ks2 + 4u;
  TF_R(13) TF_R(15) TF_R(26) TF_R(6)
  x0 += ks2; x1 += k0 + 5u;
#undef TF_R
  *o0 = x0; *o1 = x1;
}

// ---- XLA ErfInv32 (Giles coefficients, exact op order) ----
__device__ inline float erfinv_xla(float x) {
#pragma clang fp contract(off)
  float w = -log1pf(-(x * x));
  float p;
  if (w < 5.0f) {
    w = w - 2.5f;
    p = 2.81022636e-08f;
    p = 3.43273939e-07f  + p * w;
    p = -3.5233877e-06f  + p * w;
    p = -4.39150654e-06f + p * w;
    p = 0.00021858087f   + p * w;
    p = -0.00125372503f  + p * w;
    p = -0.00417768164f  + p * w;
    p = 0.246640727f     + p * w;
    p = 1.50140941f      + p * w;
  } else {
    w = sqrtf(w) - 3.0f;
    p = -0.000200214257f;
    p = 0.000100950558f  + p * w;
    p = 0.00134934322f   + p * w;
    p = -0.00367342844f  + p * w;
    p = 0.00573950773f   + p * w;
    p = -0.0076224613f   + p * w;
    p = 0.00943887047f   + p * w;
    p = 1.00167406f      + p * w;
    p = 2.83297682f      + p * w;
  }
  return p * x;
}

// jax.random.normal element `idx` of a (4,64,64,2) f32 draw under key (k0,k1).
// threefry_partitionable=True stream: counter = flat index, bits = o0 ^ o1.
__device__ inline float jax_normal(uint32_t k0, uint32_t k1, uint32_t idx) {
#pragma clang fp contract(off)
  uint32_t o0, o1;
  tf2x32(k0, k1, 0u, idx, &o0, &o1);
  uint32_t bits = o0 ^ o1;
  float f = __uint_as_float((bits >> 9) | 0x3f800000u) - 1.0f;
  float u = f * 2.0f + (-0x1.fffffep-1f);
  u = fmaxf(-0x1.fffffep-1f, u);
  return 0x1.6a09e6p+0f * erfinv_xla(u);  // float(sqrt(2)) * erfinv(u)
}

// Bilinear corr score; association matches XLA: ((t00+t01)+t10)+t11.
__device__ inline float score_at(const float* __restrict__ base, int stride,
                                 float x, float y) {
#pragma clang fp contract(off)
  float x0 = floorf(x), y0 = floorf(y);
  float wx = x - x0, wy = y - y0;
  int xi = (int)x0; xi = xi < 0 ? 0 : (xi > 63 ? 63 : xi);
  int yi = (int)y0; yi = yi < 0 ? 0 : (yi > 63 ? 63 : yi);
  int x1 = xi + 1 > 63 ? 63 : xi + 1;
  int y1 = yi + 1 > 63 ? 63 : yi + 1;
  float v00 = base[(yi * 64 + xi) * stride];
  float v01 = base[(yi * 64 + x1) * stride];
  float v10 = base[(y1 * 64 + xi) * stride];
  float v11 = base[(y1 * 64 + x1) * stride];
  float omx = 1.0f - wx, omy = 1.0f - wy;
  return (((v00 * omx) * omy + (v01 * wx) * omy) + (v10 * omx) * wy) + (v11 * wx) * wy;
}

// Fused propagate(+optional random-search) step. One pixel per thread,
// 512 blocks x 64 threads -> all 256 CUs active. Kernel-launch boundary is
// the global barrier between steps; coords double-buffer in d_ws.
// rs old-score reuses the propagate best_s: the winning candidate's score was
// computed in this kernel from identical loads/ops, so bits match the
// reference's recomputation exactly.
__global__ __launch_bounds__(64) void step_kernel(
    const float* __restrict__ mf, const float* __restrict__ mb,
    const float2* __restrict__ in_c, float2* __restrict__ out_c,
    const float* __restrict__ corr, int dx, int dy,
    uint32_t k0f, uint32_t k1f, uint32_t k0b, uint32_t k1b,
    int do_rs, int from_matching) {
#pragma clang fp contract(off)
  int g = (int)(blockIdx.x * 64 + threadIdx.x);   // 0..32767
  int dir = g >> 14, b = (g >> 12) & 3, p = g & 4095;
  int i = p >> 6, j = p & 63;

  const float* base; int stride;
  if (dir == 0) { base = corr + (size_t)(b * 4096 + p) * 4096; stride = 1; }
  else          { base = corr + (size_t)b * 16777216 + p;      stride = 4096; }

  float2 c, ch, cv;
  int jh = (j - dx) & 63;            // roll along W
  int iv = (i - dy) & 63;            // roll along H
  if (from_matching) {
    const float* m = dir ? mb : mf;
    c  = make_float2(m[((b * 2 + 0) * 64 + i ) * 64 + j ], m[((b * 2 + 1) * 64 + i ) * 64 + j ]);
    ch = make_float2(m[((b * 2 + 0) * 64 + i ) * 64 + jh], m[((b * 2 + 1) * 64 + i ) * 64 + jh]);
    cv = make_float2(m[((b * 2 + 0) * 64 + iv) * 64 + j ], m[((b * 2 + 1) * 64 + iv) * 64 + j ]);
  } else {
    const float2* ic = in_c + dir * 16384 + b * 4096;
    c  = ic[p];
    ch = ic[(i << 6) | jh];
    cv = ic[(iv << 6) | j];
  }
  ch.x = fminf(fmaxf(ch.x + (float)dx, 0.0f), 63.0f);  // + [dx,0], clamp
  cv.y = fminf(fmaxf(cv.y + (float)dy, 0.0f), 63.0f);  // + [0,dy], clamp

  float s0 = score_at(base, stride, c.x,  c.y);
  float sh = score_at(base, stride, ch.x, ch.y);
  float sv = score_at(base, stride, cv.x, cv.y);
  float2 bst = c; float bs = s0;
  if (sh > bs) bst = ch;                // upd = s > best_s
  bs = fmaxf(sh, bs);
  if (sv > bs) bst = cv;
  bs = fmaxf(sv, bs);

  if (do_rs) {
    uint32_t kk0 = dir ? k0b : k0f, kk1 = dir ? k1b : k1f;
    uint32_t pg = (uint32_t)(b * 4096 + p);        // flat (b,i,j) over (4,64,64)
    float n0 = jax_normal(kk0, kk1, 2u * pg);
    float n1 = jax_normal(kk0, kk1, 2u * pg + 1u);
    float nx = fminf(fmaxf(bst.x + 3.0f * n0, 0.0f), 63.0f);
    float ny = fminf(fmaxf(bst.y + 3.0f * n1, 0.0f), 63.0f);
    float sn = score_at(base, stride, nx, ny);
    if (sn - bs > 0.0f) bst = make_float2(nx, ny);  // new_s - 1.0*old_s > 0
  }
  out_c[dir * 16384 + b * 4096 + p] = bst;
}

// Bilinear-sample res_b at res_f, fwd-bwd consistency, transpose to (B,2,H,W).
__global__ __launch_bounds__(256) void combine_kernel(const float* __restrict__ mf,
                                                      const float2* __restrict__ res,
                                                      float* __restrict__ out) {
#pragma clang fp contract(off)
  int pg = (int)(blockIdx.x * 256 + threadIdx.x);   // 0..16383
  int b = pg >> 12, hw = pg & 4095;
  int i = hw >> 6, j = hw & 63;
  float2 rf = res[pg];
  const float2* rb = res + 16384 + b * 4096;
  float x0 = floorf(rf.x), y0 = floorf(rf.y);
  float wx = rf.x - x0, wy = rf.y - y0;
  int xi = (int)x0; xi = xi < 0 ? 0 : (xi > 63 ? 63 : xi);
  int yi = (int)y0; yi = yi < 0 ? 0 : (yi > 63 ? 63 : yi);
  int x1 = xi + 1 > 63 ? 63 : xi + 1;
  int y1 = yi + 1 > 63 ? 63 : yi + 1;
  float2 v00 = rb[yi * 64 + xi], v01 = rb[yi * 64 + x1];
  float2 v10 = rb[y1 * 64 + xi], v11 = rb[y1 * 64 + x1];
  float omx = 1.0f - wx, omy = 1.0f - wy;
  float c0 = (((v00.x * omx) * omy + (v01.x * wx) * omy) + (v10.x * omx) * wy) + (v11.x * wx) * wy;
  float c1 = (((v00.y * omx) * omy + (v01.y * wx) * omy) + (v10.y * omx) * wy) + (v11.y * wx) * wy;
  float d = fmaxf(fabsf(rf.x - c0), fabsf(rf.y - c1));
  bool invalid = d > 0.01f;
  out[((b * 2 + 0) * 64 + i) * 64 + j] = invalid ? mf[((b * 2 + 0) * 64 + i) * 64 + j] : rf.x;
  out[((b * 2 + 1) * 64 + i) * 64 + j] = invalid ? mf[((b * 2 + 1) * 64 + i) * 64 + j] : rf.y;
}

extern "C" void kernel_launch(void* const* d_in, const int* in_sizes, int n_in,
                              void* d_out, int out_size, void* d_ws, size_t ws_size,
                              hipStream_t stream) {
  const float* mf   = (const float*)d_in[0];
  const float* mb   = (const float*)d_in[1];
  const float* corr = (const float*)d_in[2];
  float* out  = (float*)d_out;
  float2* bufA = (float2*)d_ws;             // [2][4][4096] float2 = 256 KB
  float2* bufB = bufA + 32768;              // second 256 KB

  // Host-side key derivation from seed 42 -> root key (0, 42).
  // split(root,2)[d] = enc_root(0, d); split(k,3)[s] = enc_k(0, s).
  uint32_t kf0, kf1, kb0, kb1, K[12];
  tf2x32(0u, 42u, 0u, 0u, &kf0, &kf1);
  tf2x32(0u, 42u, 0u, 1u, &kb0, &kb1);
  for (uint32_t s = 0; s < 3; ++s) {
    tf2x32(kf0, kf1, 0u, s, &K[0 + s * 2], &K[0 + s * 2 + 1]);
    tf2x32(kb0, kb1, 0u, s, &K[6 + s * 2], &K[6 + s * 2 + 1]);
  }

  dim3 grid(512), block(64);
  // step 1: propagate(+1,+1) from matching, + random_search(k1)
  step_kernel<<<grid, block, 0, stream>>>(mf, mb, nullptr, bufA, corr,  1,  1,
                                          K[0], K[1], K[6], K[7], 1, 1);
  // step 2: propagate(-1,-1), + random_search(k2)
  step_kernel<<<grid, block, 0, stream>>>(mf, mb, bufA, bufB, corr, -1, -1,
                                          K[2], K[3], K[8], K[9], 1, 0);
  // step 3: propagate(-1,+1), + random_search(k3)
  step_kernel<<<grid, block, 0, stream>>>(mf, mb, bufB, bufA, corr, -1,  1,
                                          K[4], K[5], K[10], K[11], 1, 0);
  // step 4: propagate(+1,-1), no rs
  step_kernel<<<grid, block, 0, stream>>>(mf, mb, bufA, bufB, corr,  1, -1,
                                          0u, 0u, 0u, 0u, 0, 0);
  combine_kernel<<<dim3(64), dim3(256), 0, stream>>>(mf, bufB, out);
  (void)in_sizes; (void)n_in; (void)out_size; (void)ws_size;
}